// Round 9
// baseline (349.663 us; speedup 1.0000x reference)
//
#include <hip/hip_runtime.h>
#include <stdint.h>

// ---------------------------------------------------------------------------
// 5-layer LSTM (H=4, IN=1, B=1024, T=2048) -> final hidden state of top layer.
//
// Layer-pipelined wavefront (5 waves = 5 layers, 4 batch el/block, 256 blocks)
// with producer-push handoff and a 13-slot serial chain:
//
//   S1  rotate R2 (row_ror DPP)           [R2 = sigma(2c) of prev step]
//   S2  u=fma(a0,R2,gxb); v=a2*r2         [a_m, gxb precomputed off-chain]
//   S2b u=fma(a1,r1,u);  v=fma(a3,r3,v)
//   S3  acc = u+v                          [= s*(Wx x + Wh h + bias)]
//   S4  E  = exp2(acc)
//   S5  A  = 1+E
//   S6  R  = rcp(A)                        [sigmoid lanes: gate value]
//   S7  act= fma(k1,R,k0)                  [g-lane: -2log2e * tanh(ag)]
//   S8  iv,fv,gv,ov = quad_perm gathers
//   S9  m  = iv*gv                         [gv pre-scaled -> c' scaled units]
//   S10 c' = fma(fv,c',m)                  [c' = -2log2e * c]
//   S11 E2 = exp2(c')
//   S12 A2 = 1+E2
//   S13 R2 = rcp(A2)                       [= sigma(2c)]
//
// Off-chain per step (in the shadow of S9..S13): rot(ov), p_m=whh_m*ovr_m,
// a_m=2p_m, b=sum p_m, gxb=gx[t+1]-b, h=fma(2ov,R2,-ov), producer push
// (rot(h) + fma tree + ds_write). Identity: sum whh_m*rot_m(h) =
// sum (2*whh_m*ovr_m)*R2r_m - sum whh_m*ovr_m  since h = ov*(2*R2-1).
//
//  - lane q (of 16 per element): hidden j=q>>2, gate gt=q&3, row r=gt*4+j.
//  - row_ror:4/8/12 delivers lane (i-N)&15 => X_{(j-m)&3}; weight columns
//    pre-rotated k=(j-m)&3 to match.
//  - weights pre-scaled: s = -log2e (sigmoid rows) / -2log2e (tanh row).
//  - handoff [boundary][parity][lane][tc] stride-33 LDS, CHUNK=32, ping-pong,
//    one __syncthreads/phase; wave-0 prefetches x; setprio around the loop.
// ---------------------------------------------------------------------------

#define T_LEN   2048
#define NLAYER  5
#define CHUNK   32
#define NCHUNK  (T_LEN / CHUNK)        // 64
#define NPHASE  (NCHUNK + NLAYER - 1)  // 68
#define ROWSTR  33                     // odd float stride: conflict-free LDS

template <int CTRL>
__device__ __forceinline__ float dppmov(float x) {
  int v = __builtin_amdgcn_mov_dpp(__float_as_int(x), CTRL, 0xF, 0xF, true);
  return __int_as_float(v);
}

// One LSTM step. Carried state: R2, c (scaled), a[4], b, h.
template <bool PUSH>
__device__ __forceinline__ void lstm_step(
    float gxb, float k1, float k0,
    const float* whh,                  // own recurrent weights (scaled,rotated)
    const float* wnx, float bnx,       // next-layer input weights/bias (PUSH)
    float& R2, float& c, float a[4], float& b, float& h,
    float* __restrict__ slot)
{
  // S1: rotate prev R2
  const float r1 = dppmov<0x124>(R2);
  const float r2 = dppmov<0x128>(R2);
  const float r3 = dppmov<0x12C>(R2);
  // S2-S3: gate preactivation tree (a_m, gxb from prev step, off-chain)
  float u = fmaf(a[0], R2, gxb);
  u = fmaf(a[1], r1, u);
  float v = a[2] * r2;
  v = fmaf(a[3], r3, v);
  const float acc = u + v;
  // S4-S7: gate activation
  const float E = __builtin_amdgcn_exp2f(acc);
  const float A = 1.f + E;
  const float R = __builtin_amdgcn_rcpf(A);
  const float act = fmaf(k1, R, k0);   // i,f,o: R ; g: -2log2e*tanh
  // S8: gather i,f,g,o of own hidden unit
  const float iv = dppmov<0x00>(act);
  const float fv = dppmov<0x55>(act);
  const float gv = dppmov<0xAA>(act);
  const float ov = dppmov<0xFF>(act);
  // S9-S10: scaled cell update
  c = fmaf(fv, c, iv * gv);
  // off-chain: next-step tree coefficients from ov
  const float o1 = dppmov<0x124>(ov);
  const float o2 = dppmov<0x128>(ov);
  const float o3 = dppmov<0x12C>(ov);
  const float p0 = whh[0] * ov;
  const float p1 = whh[1] * o1;
  const float p2 = whh[2] * o2;
  const float p3 = whh[3] * o3;
  b = (p0 + p1) + (p2 + p3);
  a[0] = p0 + p0; a[1] = p1 + p1; a[2] = p2 + p2; a[3] = p3 + p3;
  // S11-S13: R2 = sigma(2c) via exp2 of scaled c
  const float E2 = __builtin_amdgcn_exp2f(c);
  const float A2 = 1.f + E2;
  R2 = __builtin_amdgcn_rcpf(A2);
  // off-chain: h (push + final output); exact limits at E2=0/inf
  h = fmaf(ov + ov, R2, -ov);
  if (PUSH) {
    const float h1 = dppmov<0x124>(h);
    const float h2 = dppmov<0x128>(h);
    const float h3 = dppmov<0x12C>(h);
    float g = fmaf(wnx[0], h, bnx);
    g = fmaf(wnx[1], h1, g);
    float g2 = wnx[2] * h2;
    g2 = fmaf(wnx[3], h3, g2);
    *slot = g + g2;
  }
}

__global__ void __launch_bounds__(64 * NLAYER, 1) lstm_pipe(
    const float* __restrict__ x,         // [1024][2048][1]
    const float* __restrict__ w_ih0,     // [16][1]
    const float* __restrict__ w_ih_rest, // [4][16][4]
    const float* __restrict__ w_hh,      // [5][16][4]
    const float* __restrict__ b_ih,      // [5][16]
    const float* __restrict__ b_hh,      // [5][16]
    float* __restrict__ out)             // [1024][4]
{
  const int tid  = threadIdx.x;
  const int l    = tid >> 6;        // wave id == layer
  const int lane = tid & 63;        // == el*16 + q
  const int q    = lane & 15;
  const int el   = lane >> 4;
  const int e    = blockIdx.x * 4 + el;
  const int gt   = q & 3;           // 0=i 1=f 2=g 3=o
  const int j    = q >> 2;          // hidden unit index
  const int r    = gt * 4 + j;      // row in 4H weight matrices

  const float LOG2E = 1.4426950408889634f;
  const float s  = (gt == 2) ? (-2.0f * LOG2E) : (-LOG2E);
  // act = fma(k1,R,k0): i,f,o lanes -> R; g-lane -> -2log2e*(2R-1)
  const float k1 = (gt == 2) ? (-4.0f * LOG2E) : 1.0f;
  const float k0 = (gt == 2) ? ( 2.0f * LOG2E) : 0.0f;

  // ---- own recurrent weights, columns rotated k=(j-m)&3, pre-scaled ----
  float whh[4];
  #pragma unroll
  for (int m = 0; m < 4; ++m)
    whh[m] = w_hh[l * 64 + r * 4 + ((j - m) & 3)] * s;

  // ---- NEXT layer's input weights + bias (producer-push), same scaling ----
  float wnx[4] = {0.f, 0.f, 0.f, 0.f};
  float bnx = 0.f;
  if (l < NLAYER - 1) {
    #pragma unroll
    for (int m = 0; m < 4; ++m)
      wnx[m] = w_ih_rest[l * 64 + r * 4 + ((j - m) & 3)] * s;   // layer l+1
    bnx = (b_ih[(l + 1) * 16 + r] + b_hh[(l + 1) * 16 + r]) * s;
  }

  // ---- own layer-0 input path ----
  float wx = 0.f, bias0 = 0.f;
  if (l == 0) {
    wx = w_ih0[r] * s;
    bias0 = (b_ih[r] + b_hh[r]) * s;
  }

  // ---- carried recurrent state ----
  float R2 = 0.5f;                  // sigma(2*0)
  float c  = 0.f;                   // scaled cell
  float a[4] = {0.f, 0.f, 0.f, 0.f};
  float b  = 0.f;
  float h  = 0.f;

  // handoff: [boundary][parity][lane-row][tc], odd row stride (67.6 KiB)
  __shared__ float buf[NLAYER - 1][2][64][ROWSTR];

  float gx[CHUNK];
  float xcur[CHUNK];   // wave-0 x prefetch buffer (holds chunk n at phase n)

  if (l == 0) {
    #pragma unroll
    for (int tc = 0; tc < CHUNK; ++tc) xcur[tc] = x[e * T_LEN + tc];
  }

  for (int p = 0; p < NPHASE; ++p) {
    const int n = p - l;                 // chunk index for this wave
    if (n >= 0 && n < NCHUNK) {
      const int par = n & 1;

      // ---- phase head: fetch ready-to-use gx for the whole chunk ----
      if (l == 0) {
        #pragma unroll
        for (int tc = 0; tc < CHUNK; ++tc)
          gx[tc] = fmaf(wx, xcur[tc], bias0);
        if (n + 1 < NCHUNK) {            // prefetch next chunk (WAR-ordered)
          #pragma unroll
          for (int tc = 0; tc < CHUNK; ++tc)
            xcur[tc] = x[e * T_LEN + (n + 1) * CHUNK + tc];
        }
      } else {
        const float* row = &buf[l - 1][par][lane][0];
        #pragma unroll
        for (int tc = 0; tc < CHUNK; ++tc) gx[tc] = row[tc];  // 32 indep loads
      }
      float gxb = gx[0] - b;     // b carried from previous chunk's last step

      // ---- serial step loop: the pipeline's critical path ----
      __builtin_amdgcn_s_setprio(1);
      if (l < NLAYER - 1) {
        float* slot = &buf[l][par][lane][0];
        #pragma unroll
        for (int tc = 0; tc < CHUNK; ++tc) {
          lstm_step<true>(gxb, k1, k0, whh, wnx, bnx, R2, c, a, b, h,
                          slot + tc);
          if (tc < CHUNK - 1) gxb = gx[tc + 1] - b;
        }
      } else {
        #pragma unroll
        for (int tc = 0; tc < CHUNK; ++tc) {
          lstm_step<false>(gxb, k1, k0, whh, nullptr, 0.f, R2, c, a, b, h,
                           nullptr);
          if (tc < CHUNK - 1) gxb = gx[tc + 1] - b;
        }
      }
      __builtin_amdgcn_s_setprio(0);
    }
    __syncthreads();   // all 5 waves, every phase (uniform)
  }

  // ---- final output: top wave's h at t = T_LEN-1 (quad-uniform) ----
  if (l == NLAYER - 1 && gt == 0) out[e * 4 + j] = h;
}

extern "C" void kernel_launch(void* const* d_in, const int* in_sizes, int n_in,
                              void* d_out, int out_size, void* d_ws, size_t ws_size,
                              hipStream_t stream) {
  const float* x     = (const float*)d_in[0];
  const float* wih0  = (const float*)d_in[1];
  const float* wrest = (const float*)d_in[2];
  const float* whh   = (const float*)d_in[3];
  const float* bih   = (const float*)d_in[4];
  const float* bhh   = (const float*)d_in[5];
  float* out = (float*)d_out;

  dim3 grid(256);            // 1024 elements / 4 per block
  dim3 block(64 * NLAYER);   // 5 waves: one per layer
  lstm_pipe<<<grid, block, 0, stream>>>(x, wih0, wrest, whh, bih, bhh, out);
}

// Round 10
// 280.769 us; speedup vs baseline: 1.2454x; 1.2454x over previous
//
#include <hip/hip_runtime.h>
#include <stdint.h>

// ---------------------------------------------------------------------------
// 5-layer LSTM (H=4, IN=1, B=1024, T=2048) -> final hidden state of top layer.
//
// Layer-pipelined wavefront (5 waves = 5 layers, 4 batch el/block, 256 blocks)
// with producer-push handoff. Serial chain per step (12 slots):
//   rot(h) DPP -> fma-tree(3) -> exp2 -> add1 -> rcp -> fma(act)
//   -> quad_perm gather -> mul -> fma(c') -> exp2 -> add1 -> rcp
// Scaled cell: c' = -2log2e * c carried; g-lane gather constants
// k1=-4log2e, k0=+2log2e deliver gv pre-scaled so exp2(c') needs no mul.
// h = fma(2ov, R2, -ov) off-chain (exact limits at E=0/inf, no clamps).
//
// R9 lesson encoded here: off-chain instructions cost ~4 cy each (issue/
// hazard on the shared SIMD) -> keep TOTAL instruction count minimal; never
// trade 1 chain slot for several off-chain ops.
//
//  - lane q (of 16 per element): hidden j=q>>2, gate gt=q&3, row r=gt*4+j
//    (PyTorch gate order i,f,g,o).
//  - row_ror:4/8/12 delivers lane (i-N)&15 => h_{(j-m)&3}; weight columns
//    pre-rotated k=(j-m)&3 to match. quad_perm 0x00/55/AA/FF gathers i/f/g/o.
//  - producer-push: wave l computes next layer's gx = b_{l+1}+W_ih^{l+1}.h
//    from its rotated h quadruple (off-chain) and writes it to LDS; consumer
//    phase head is 32 independent ds_read_b32.
//  - handoff [boundary][parity][lane][tc] stride-33 LDS (2-way bank alias =
//    free), CHUNK=32, ping-pong parity.
//  - barrier = "s_waitcnt lgkmcnt(0); s_barrier" (NO vmcnt drain): LDS
//    ordering preserved; wave-0's x-prefetch loads may stay in flight.
//  - weights pre-scaled: s = -log2e (sigmoid rows) / -2log2e (tanh row).
// ---------------------------------------------------------------------------

#define T_LEN   2048
#define NLAYER  5
#define CHUNK   32
#define NCHUNK  (T_LEN / CHUNK)        // 64
#define NPHASE  (NCHUNK + NLAYER - 1)  // 68
#define ROWSTR  33                     // odd float stride: conflict-free LDS

template <int CTRL>
__device__ __forceinline__ float dppmov(float x) {
  int v = __builtin_amdgcn_mov_dpp(__float_as_int(x), CTRL, 0xF, 0xF, true);
  return __int_as_float(v);
}

// LDS-ordering barrier WITHOUT vmcnt drain.
__device__ __forceinline__ void barrier_lds() {
  asm volatile("s_waitcnt lgkmcnt(0)\n\ts_barrier" ::: "memory");
}

// One LSTM step on the serial critical path. Updates (hr0..hr3, c') in place.
// PUSH: compute next layer's gx from h and publish to the LDS slot.
template <bool PUSH>
__device__ __forceinline__ void lstm_step(
    float gxv, const float* whh, float k1, float k0,
    const float* wnx, float bnx,       // next-layer input weights/bias (PUSH)
    float& hr0, float& hr1, float& hr2, float& hr3, float& c,
    float* __restrict__ slot)          // &buf[l][par][lane][tc] when PUSH
{
  // ---- recurrent pre-activation (tree) ----
  float t01 = fmaf(whh[0], hr0, gxv);
  t01 = fmaf(whh[1], hr1, t01);
  float t23 = whh[2] * hr2;
  t23 = fmaf(whh[3], hr3, t23);
  const float acc = t01 + t23;

  // ---- gate activation: R = 1/(1+2^acc); act = k1*R + k0 ----
  // i,f,o lanes: act = sigmoid; g lane: act = -2log2e * tanh (pre-scaled)
  const float E = __builtin_amdgcn_exp2f(acc);
  const float A = 1.f + E;
  const float R = __builtin_amdgcn_rcpf(A);
  const float act = fmaf(k1, R, k0);

  // ---- gather i,f,g,o of own hidden unit (quad_perm) ----
  const float iv = dppmov<0x00>(act);
  const float fv = dppmov<0x55>(act);
  const float gv = dppmov<0xAA>(act);   // already scaled by -2log2e
  const float ov = dppmov<0xFF>(act);
  const float ov2 = ov + ov;     // off-chain
  const float ovm = -ov;         // off-chain (folds to fma neg modifier)

  // ---- scaled cell: c' = fma(fv, c', iv*gv); R2 = sigma(2c) ----
  c = fmaf(fv, c, iv * gv);
  const float E2 = __builtin_amdgcn_exp2f(c);
  const float A2 = 1.f + E2;
  const float R2 = __builtin_amdgcn_rcpf(A2);
  const float h  = fmaf(ov2, R2, ovm);  // o * tanh(c), exact limits

  // ---- rotated h quadruple for next step: hr_m = h_{(j-m)&3} ----
  hr0 = h;
  hr1 = dppmov<0x124>(h);
  hr2 = dppmov<0x128>(h);
  hr3 = dppmov<0x12C>(h);

  // ---- producer-push: next layer's gx (off the critical chain) ----
  if (PUSH) {
    float g = fmaf(wnx[0], hr0, bnx);
    g = fmaf(wnx[1], hr1, g);
    float g2 = wnx[2] * hr2;
    g2 = fmaf(wnx[3], hr3, g2);
    *slot = g + g2;
  }
}

__global__ void __launch_bounds__(64 * NLAYER, 1) lstm_pipe(
    const float* __restrict__ x,         // [1024][2048][1]
    const float* __restrict__ w_ih0,     // [16][1]
    const float* __restrict__ w_ih_rest, // [4][16][4]
    const float* __restrict__ w_hh,      // [5][16][4]
    const float* __restrict__ b_ih,      // [5][16]
    const float* __restrict__ b_hh,      // [5][16]
    float* __restrict__ out)             // [1024][4]
{
  const int tid  = threadIdx.x;
  const int l    = tid >> 6;        // wave id == layer
  const int lane = tid & 63;        // == el*16 + q
  const int q    = lane & 15;
  const int el   = lane >> 4;
  const int e    = blockIdx.x * 4 + el;
  const int gt   = q & 3;           // 0=i 1=f 2=g 3=o
  const int j    = q >> 2;          // hidden unit index
  const int r    = gt * 4 + j;      // row in 4H weight matrices

  const float LOG2E = 1.4426950408889634f;
  const float s  = (gt == 2) ? (-2.0f * LOG2E) : (-LOG2E);
  // act = fma(k1,R,k0): i,f,o -> R ; g -> -2log2e*(2R-1) = -2log2e*tanh
  const float k1 = (gt == 2) ? (-4.0f * LOG2E) : 1.0f;
  const float k0 = (gt == 2) ? ( 2.0f * LOG2E) : 0.0f;

  // ---- own recurrent weights, columns rotated k=(j-m)&3, pre-scaled ----
  float whh[4];
  #pragma unroll
  for (int m = 0; m < 4; ++m)
    whh[m] = w_hh[l * 64 + r * 4 + ((j - m) & 3)] * s;

  // ---- NEXT layer's input weights + bias (producer-push), same scaling ----
  float wnx[4] = {0.f, 0.f, 0.f, 0.f};
  float bnx = 0.f;
  if (l < NLAYER - 1) {
    #pragma unroll
    for (int m = 0; m < 4; ++m)
      wnx[m] = w_ih_rest[l * 64 + r * 4 + ((j - m) & 3)] * s;   // layer l+1
    bnx = (b_ih[(l + 1) * 16 + r] + b_hh[(l + 1) * 16 + r]) * s;
  }

  // ---- own layer-0 input path ----
  float wx = 0.f, bias0 = 0.f;
  if (l == 0) {
    wx = w_ih0[r] * s;
    bias0 = (b_ih[r] + b_hh[r]) * s;
  }

  // ---- recurrent state: rotated h quadruple + scaled cell ----
  float hr0 = 0.f, hr1 = 0.f, hr2 = 0.f, hr3 = 0.f;
  float c = 0.f;                    // c' = -2log2e * c

  // handoff: [boundary][parity][lane-row][tc], odd row stride (67.6 KiB)
  __shared__ float buf[NLAYER - 1][2][64][ROWSTR];

  float gx[CHUNK];
  float xcur[CHUNK];   // wave-0 x prefetch buffer (holds chunk n at phase n)

  if (l == 0) {
    #pragma unroll
    for (int tc = 0; tc < CHUNK; ++tc) xcur[tc] = x[e * T_LEN + tc];
  }

  for (int p = 0; p < NPHASE; ++p) {
    const int n = p - l;                 // chunk index for this wave
    if (n >= 0 && n < NCHUNK) {
      const int par = n & 1;

      // ---- phase head: fetch ready-to-use gx for the whole chunk ----
      if (l == 0) {
        #pragma unroll
        for (int tc = 0; tc < CHUNK; ++tc)
          gx[tc] = fmaf(wx, xcur[tc], bias0);
        if (n + 1 < NCHUNK) {            // prefetch next chunk (WAR-ordered)
          #pragma unroll
          for (int tc = 0; tc < CHUNK; ++tc)
            xcur[tc] = x[e * T_LEN + (n + 1) * CHUNK + tc];
        }
      } else {
        const float* row = &buf[l - 1][par][lane][0];
        #pragma unroll
        for (int tc = 0; tc < CHUNK; ++tc) gx[tc] = row[tc];  // 32 indep loads
      }

      // ---- serial step loop: the pipeline's critical path ----
      __builtin_amdgcn_s_setprio(1);
      if (l < NLAYER - 1) {
        float* slot = &buf[l][par][lane][0];
        #pragma unroll
        for (int tc = 0; tc < CHUNK; ++tc)
          lstm_step<true>(gx[tc], whh, k1, k0, wnx, bnx,
                          hr0, hr1, hr2, hr3, c, slot + tc);
      } else {
        #pragma unroll
        for (int tc = 0; tc < CHUNK; ++tc)
          lstm_step<false>(gx[tc], whh, k1, k0, nullptr, 0.f,
                           hr0, hr1, hr2, hr3, c, nullptr);
      }
      __builtin_amdgcn_s_setprio(0);
    }
    barrier_lds();   // lgkmcnt(0)+s_barrier, no vmcnt drain; uniform
  }

  // ---- final output: top wave's hr0 == h at t = T_LEN-1 ----
  if (l == NLAYER - 1 && gt == 0) out[e * 4 + j] = hr0;
}

extern "C" void kernel_launch(void* const* d_in, const int* in_sizes, int n_in,
                              void* d_out, int out_size, void* d_ws, size_t ws_size,
                              hipStream_t stream) {
  const float* x     = (const float*)d_in[0];
  const float* wih0  = (const float*)d_in[1];
  const float* wrest = (const float*)d_in[2];
  const float* whh   = (const float*)d_in[3];
  const float* bih   = (const float*)d_in[4];
  const float* bhh   = (const float*)d_in[5];
  float* out = (float*)d_out;

  dim3 grid(256);            // 1024 elements / 4 per block
  dim3 block(64 * NLAYER);   // 5 waves: one per layer
  lstm_pipe<<<grid, block, 0, stream>>>(x, wih0, wrest, whh, bih, bhh, out);
}